// Round 21
// baseline (2308.572 us; speedup 1.0000x reference)
//
#include <hip/hip_runtime.h>
#include <hip/hip_bf16.h>

// NCA2D: B=16, H=128, W=128, C=16, T=8, HID=128, N_STEPS=64, FC0_IN=49
constexpr int B = 16, H = 128, W = 128, C = 16, T = 8, HID = 128, NSTEPS = 64;

using f32x4  = __attribute__((ext_vector_type(4))) float;
using bf16x8 = __attribute__((ext_vector_type(8))) short;

__device__ __forceinline__ unsigned short bf16_hi(float v) {
    __hip_bfloat16 h = __float2bfloat16(v);
    return *reinterpret_cast<unsigned short*>(&h);
}
__device__ __forceinline__ float bf16_f32(unsigned short u) {
    union { unsigned int u; float f; } c; c.u = ((unsigned int)u) << 16; return c.f;
}

// Packed fragment table (24 rows x 64 lanes x 16B = 24KB):
//  rows 0..15 : fc0 B-frags HI only, row = nt*2 + half
//  rows 16..23: fc1 A-frags (W1), row = 16 + ks*2 + f, f in {hi,lo}
__global__ void prep_pack(const float* __restrict__ fc0_w, const float* __restrict__ fc1_w,
                          unsigned short* __restrict__ pack) {
    for (int e = threadIdx.x; e < 24 * 64; e += 256) {
        const int row = e >> 6, l = e & 63;
        const int m = l & 15, g = l >> 4;
        unsigned short v[8];
        if (row < 16) {
            const int nt = row >> 1, half = row & 1;
            const int n = nt * 16 + m;
            const int kbase = half * 32 + g * 8;
            #pragma unroll
            for (int j = 0; j < 8; ++j) {
                const int k = kbase + j;
                v[j] = (k < 49) ? bf16_hi(fc0_w[n * 49 + k]) : (unsigned short)0;
            }
        } else {
            const int rr = row - 16, ks = rr >> 1, f = rr & 1;
            #pragma unroll
            for (int j = 0; j < 8; ++j) {
                const float x = fc1_w[m * HID + ks * 32 + g * 8 + j];
                const unsigned short hi = bf16_hi(x);
                v[j] = f ? bf16_hi(x - bf16_f32(hi)) : hi;
            }
        }
        #pragma unroll
        for (int j = 0; j < 8; ++j) pack[e * 8 + j] = v[j];
    }
}

// Zero only output slots whose acquire step is 0 (never snapshot-written).
__global__ void zero_acq0(const int* __restrict__ acq, float* __restrict__ out) {
    const int bt = blockIdx.x;
    if (acq[bt] != 0) return;
    float4* p = reinterpret_cast<float4*>(out + (size_t)bt * (H * W * C));
    for (int i = threadIdx.x; i < (H * W * C) / 4; i += 256)
        p[i] = make_float4(0.0f, 0.0f, 0.0f, 0.0f);
}

// R19 body (1819us best) with fc0 weight frags moved LDS -> REGISTERS:
// each lane only ever reads its own 16 entries (b0h/b1h x 8 nt = 64 VGPR),
// held across all 4 tiles. Removes 16 ds_read_b128/tile, the 16KB/block/step
// staging traffic, and shrinks LDS 34->17.6KB. VGPR ~84 -> ~150-170, still
// under the (256,2) 256-reg cap. LESSONS kept: caps <256 regs spill the
// unified VGPR+AGPR file (R15); cooperative launch fails here (R17).
__global__ __launch_bounds__(256, 2) void nca_step(
    const float* __restrict__ x_in, float* __restrict__ x_out,
    const float* __restrict__ p0_w, const float* __restrict__ p0_b,
    const float* __restrict__ p1_w, const float* __restrict__ p1_b,
    const unsigned short* __restrict__ pack, const float* __restrict__ fc0_b,
    const int* __restrict__ acq, float* __restrict__ out, int step)
{
    __shared__ __align__(16) unsigned short hlds[4 * 2048];  // per-wave h bf16 [16][128] (16KB)
    __shared__ float cwl[2][144];                            // conv weights
    __shared__ float cbl[2][16];                             // conv biases

    const int tid  = threadIdx.x;
    const int wv   = tid >> 6;
    const int lane = tid & 63;
    const int m    = lane & 15;
    const int g    = lane >> 4;

    // ---- stage conv weights global->LDS (tiny)
    if (tid < 144) { cwl[0][tid] = p0_w[tid]; cwl[1][tid] = p1_w[tid]; }
    else if (tid < 160) { cbl[0][tid - 144] = p0_b[tid - 144]; cbl[1][tid - 144] = p1_b[tid - 144]; }

    // ---- fc0 + fc1 weight frags straight to registers (L2-resident 24KB table)
    bf16x8 w0f[16];   // [nt*2+half], this lane's fc0 B-frags
    #pragma unroll
    for (int q = 0; q < 16; ++q)
        w0f[q] = *reinterpret_cast<const bf16x8*>(pack + ((size_t)(q * 64 + lane)) * 8);
    bf16x8 w1f[8];    // fc1 A-frags (W1 hi/lo), rows 16..23
    #pragma unroll
    for (int q = 0; q < 8; ++q)
        w1f[q] = *reinterpret_cast<const bf16x8*>(pack + ((size_t)((16 + q) * 64 + lane)) * 8);
    float bias[8];
    #pragma unroll
    for (int nt = 0; nt < 8; ++nt) bias[nt] = fc0_b[nt * 16 + m];

    // XCD-bijective swizzle: consecutive swizzled ids share an XCD's L2 (halo reuse)
    const int bid = (blockIdx.x & 7) * 128 + (blockIdx.x >> 3);
    const int blockbase = bid * 256;
    const int b = blockbase >> 14;

    const int ch = (g & 1) * 8;
    unsigned short* hb = hlds + (wv << 11);
    const float prog = (float)step * (1.0f / (float)NSTEPS);

    int snapmask = 0;
    if (step > 0) {
        #pragma unroll
        for (int t = 0; t < T; ++t)
            snapmask |= (acq[b * T + t] == step) ? (1 << t) : 0;
    }

    __syncthreads();   // conv-weight staging visible

    const float* pwl = (g >= 2) ? cwl[0] : cwl[1];
    const float* pbl = (g >= 2) ? cbl[0] : cbl[1];

    for (int t = 0; t < 4; ++t) {
        const int cellbase = blockbase + t * 64 + wv * 16;
        const int hrow  = (cellbase >> 7) & (H - 1);
        const int wbase = cellbase & (W - 1);
        const int wcol  = wbase + m;

        // ---- depthwise conv: lane (g,m) -> 8 ch of one conv at cell cellbase+m
        // g0: z2 ch0-7 | g1: z2 ch8-15 | g2: z1 ch0-7 | g3: z1 ch8-15
        float z[8], xcen[8];
        #pragma unroll
        for (int j = 0; j < 8; ++j) z[j] = pbl[ch + j];
        #pragma unroll
        for (int di = -1; di <= 1; ++di) {
            int hh = hrow + di; hh = (hh < 0) ? 1 : ((hh > H - 1) ? H - 2 : hh);
            #pragma unroll
            for (int dj = -1; dj <= 1; ++dj) {
                int ww = wcol + dj; ww = (ww < 0) ? 1 : ((ww > W - 1) ? W - 2 : ww);
                const float4* p4 = reinterpret_cast<const float4*>(
                    x_in + (((size_t)(b * H + hh) * W + ww) << 4) + ch);
                const float4 q0 = p4[0], q1 = p4[1];
                const float xv[8] = {q0.x, q0.y, q0.z, q0.w, q1.x, q1.y, q1.z, q1.w};
                const int tap = (di + 1) * 3 + (dj + 1);
                #pragma unroll
                for (int j = 0; j < 8; ++j)
                    z[j] = fmaf(xv[j], pwl[tap * 16 + ch + j], z[j]);
                if (di == 0 && dj == 0) {
                    #pragma unroll
                    for (int j = 0; j < 8; ++j) xcen[j] = xv[j];
                }
            }
        }
        const float4 xold4 = *reinterpret_cast<const float4*>(
            x_in + ((size_t)(cellbase + m) << 4) + (g << 2));

        // ---- A-frags (K=64: k0-31 = [x | z1], k32-63 = [z2 | prog | pad])
        bf16x8 a0h, a0l, a1h, a1l;
        #pragma unroll
        for (int j = 0; j < 8; ++j) {
            const float f0 = (g < 2) ? xcen[j] : z[j];
            const float f1 = (g < 2) ? z[j] : ((g == 2 && j == 0) ? prog : 0.0f);
            const unsigned short h0 = bf16_hi(f0);
            a0h[j] = (short)h0;  a0l[j] = (short)bf16_hi(f0 - bf16_f32(h0));
            const unsigned short h1 = bf16_hi(f1);
            a1h[j] = (short)h1;  a1l[j] = (short)bf16_hi(f1 - bf16_f32(h1));
        }

        // ---- fc0: (a_hi + a_lo) x b_hi per k-half; B-frags from registers;
        //      store h as bf16-hi: lane(g,m) reg r -> h[cell g*4+r][hid nt*16+m]
        __builtin_amdgcn_s_setprio(1);
        #pragma unroll
        for (int nt = 0; nt < 8; ++nt) {
            f32x4 acc = {0.0f, 0.0f, 0.0f, 0.0f};
            acc = __builtin_amdgcn_mfma_f32_16x16x32_bf16(a0h, w0f[nt * 2 + 0], acc, 0, 0, 0);
            acc = __builtin_amdgcn_mfma_f32_16x16x32_bf16(a0l, w0f[nt * 2 + 0], acc, 0, 0, 0);
            acc = __builtin_amdgcn_mfma_f32_16x16x32_bf16(a1h, w0f[nt * 2 + 1], acc, 0, 0, 0);
            acc = __builtin_amdgcn_mfma_f32_16x16x32_bf16(a1l, w0f[nt * 2 + 1], acc, 0, 0, 0);
            // gran = hid>>3 = nt*2 + (m>>3); swizzled gran' = gran ^ cr (4-bit XOR)
            const int gran = (nt << 1) | (m >> 3);
            #pragma unroll
            for (int r = 0; r < 4; ++r) {
                const int cr = g * 4 + r;
                hb[cr * 128 + ((gran ^ cr) << 3) + (m & 7)] =
                    bf16_hi(fmaxf(acc[r] + bias[nt], 0.0f));
            }
        }
        __builtin_amdgcn_s_setprio(0);
        // no block barrier: hlds is wave-private, within-wave DS ordering suffices

        // ---- fc1 swapped (D2 = W1 . h^T), 2 products: w1hi*h_hi + w1lo*h_hi
        f32x4 acc2 = {0.0f, 0.0f, 0.0f, 0.0f};
        #pragma unroll
        for (int ks = 0; ks < 4; ++ks) {
            const bf16x8 bh = *reinterpret_cast<const bf16x8*>(
                &hb[m * 128 + ((((ks << 2) + g) ^ m) << 3)]);
            __builtin_amdgcn_s_setprio(1);
            acc2 = __builtin_amdgcn_mfma_f32_16x16x32_bf16(w1f[ks * 2 + 0], bh, acc2, 0, 0, 0);
            acc2 = __builtin_amdgcn_mfma_f32_16x16x32_bf16(w1f[ks * 2 + 1], bh, acc2, 0, 0, 0);
            __builtin_amdgcn_s_setprio(0);
        }

        // ---- epilogue: D2 lane(g,m) reg r -> dx[ch g*4+r][cell cellbase+m]
        const size_t cell = (size_t)(cellbase + m);
        float4 xn;
        xn.x = xold4.x + 1.0f / (1.0f + __expf(-acc2[0]));
        xn.y = xold4.y + 1.0f / (1.0f + __expf(-acc2[1]));
        xn.z = xold4.z + 1.0f / (1.0f + __expf(-acc2[2]));
        xn.w = xold4.w + 1.0f / (1.0f + __expf(-acc2[3]));
        *reinterpret_cast<float4*>(x_out + (cell << 4) + (g << 2)) = xn;
        if (snapmask) {
            #pragma unroll
            for (int tt = 0; tt < T; ++tt) {
                if (snapmask & (1 << tt)) {
                    *reinterpret_cast<float4*>(out + (size_t)(b * T + tt) * (H * W * C)
                        + (((size_t)hrow * W + wbase + m) << 4) + (g << 2)) = xn;
                }
            }
        }
    }
}

extern "C" void kernel_launch(void* const* d_in, const int* in_sizes, int n_in,
                              void* d_out, int out_size, void* d_ws, size_t ws_size,
                              hipStream_t stream) {
    const float* inputs = (const float*)d_in[0];
    const int*   acq    = (const int*)d_in[1];
    const float* p0_w   = (const float*)d_in[2];
    const float* p0_b   = (const float*)d_in[3];
    const float* p1_w   = (const float*)d_in[4];
    const float* p1_b   = (const float*)d_in[5];
    const float* fc0_w  = (const float*)d_in[6];
    const float* fc0_b  = (const float*)d_in[7];
    const float* fc1_w  = (const float*)d_in[8];
    float* out = (float*)d_out;

    const size_t state_elems = (size_t)B * H * W * C;   // 16 MB each
    float* bufA = (float*)d_ws;
    float* bufB = bufA + state_elems;
    unsigned short* pack = (unsigned short*)(bufB + state_elems);  // 24 KB

    zero_acq0<<<B * T, 256, 0, stream>>>(acq, out);
    prep_pack<<<1, 256, 0, stream>>>(fc0_w, fc1_w, pack);

    const int n_cells = B * H * W;                 // 262144
    const dim3 grid(n_cells / 256), block(256);    // 1024 blocks, 4 tiles each

    const float* xin = inputs;
    for (int step = 0; step < NSTEPS; ++step) {
        float* xout = (step & 1) ? bufB : bufA;
        nca_step<<<grid, block, 0, stream>>>(
            xin, xout, p0_w, p0_b, p1_w, p1_b,
            pack, fc0_b, acq, out, step);
        xin = xout;
    }
}

// Round 22
// 1818.787 us; speedup vs baseline: 1.2693x; 1.2693x over previous
//
#include <hip/hip_runtime.h>
#include <hip/hip_bf16.h>

// NCA2D: B=16, H=128, W=128, C=16, T=8, HID=128, N_STEPS=64, FC0_IN=49
constexpr int B = 16, H = 128, W = 128, C = 16, T = 8, HID = 128, NSTEPS = 64;

using f32x4  = __attribute__((ext_vector_type(4))) float;
using bf16x8 = __attribute__((ext_vector_type(8))) short;

__device__ __forceinline__ unsigned short bf16_hi(float v) {
    __hip_bfloat16 h = __float2bfloat16(v);
    return *reinterpret_cast<unsigned short*>(&h);
}
__device__ __forceinline__ float bf16_f32(unsigned short u) {
    union { unsigned int u; float f; } c; c.u = ((unsigned int)u) << 16; return c.f;
}

// Packed fragment table (24 rows x 64 lanes x 16B = 24KB):
//  rows 0..15 : fc0 B-frags HI only, row = nt*2 + half
//  rows 16..23: fc1 A-frags (W1), row = 16 + ks*2 + f, f in {hi,lo}
__global__ void prep_pack(const float* __restrict__ fc0_w, const float* __restrict__ fc1_w,
                          unsigned short* __restrict__ pack) {
    for (int e = threadIdx.x; e < 24 * 64; e += 256) {
        const int row = e >> 6, l = e & 63;
        const int m = l & 15, g = l >> 4;
        unsigned short v[8];
        if (row < 16) {
            const int nt = row >> 1, half = row & 1;
            const int n = nt * 16 + m;
            const int kbase = half * 32 + g * 8;
            #pragma unroll
            for (int j = 0; j < 8; ++j) {
                const int k = kbase + j;
                v[j] = (k < 49) ? bf16_hi(fc0_w[n * 49 + k]) : (unsigned short)0;
            }
        } else {
            const int rr = row - 16, ks = rr >> 1, f = rr & 1;
            #pragma unroll
            for (int j = 0; j < 8; ++j) {
                const float x = fc1_w[m * HID + ks * 32 + g * 8 + j];
                const unsigned short hi = bf16_hi(x);
                v[j] = f ? bf16_hi(x - bf16_f32(hi)) : hi;
            }
        }
        #pragma unroll
        for (int j = 0; j < 8; ++j) pack[e * 8 + j] = v[j];
    }
}

// Zero only output slots whose acquire step is 0 (never snapshot-written).
__global__ void zero_acq0(const int* __restrict__ acq, float* __restrict__ out) {
    const int bt = blockIdx.x;
    if (acq[bt] != 0) return;
    float4* p = reinterpret_cast<float4*>(out + (size_t)bt * (H * W * C));
    for (int i = threadIdx.x; i < (H * W * C) / 4; i += 256)
        p[i] = make_float4(0.0f, 0.0f, 0.0f, 0.0f);
}

// FINAL = R19 (measured best 1819us, absmax 0.75): R16 body with h stored in
// LDS as BF16-HI (hlds 32->16KB, total LDS ~34KB -> 4 blocks/CU); fc0 =
// (a_hi+a_lo) x b_hi from LDS-staged frags (4 MFMA/nt); fc1 = 2 products
// (w1hi*h_hi + w1lo*h_hi); setprio(1) on MFMA clusters; XCD-bijective block
// swizzle; conv weights in LDS.
// CLOSED AXES (measured): launch_bounds caps <256 regs spill the unified
// VGPR+AGPR file to scratch, 100-400MB/step (R15); VGPR-for-LDS trades lose
// occupancy (R21: fc0 weights in regs 1819->2308); hand ILP pipelining
// neutral-negative (R8/R9); shuffle-gather transpose spills (R11/R12);
// cooperative launch unsupported here (R17).
__global__ __launch_bounds__(256, 2) void nca_step(
    const float* __restrict__ x_in, float* __restrict__ x_out,
    const float* __restrict__ p0_w, const float* __restrict__ p0_b,
    const float* __restrict__ p1_w, const float* __restrict__ p1_b,
    const unsigned short* __restrict__ pack, const float* __restrict__ fc0_b,
    const int* __restrict__ acq, float* __restrict__ out, int step)
{
    __shared__ float wlds[16 * 256];                         // fc0 hi B-frags (16KB)
    __shared__ __align__(16) unsigned short hlds[4 * 2048];  // per-wave h bf16 [16][128] (16KB)
    __shared__ float cwl[2][144];                            // conv weights
    __shared__ float cbl[2][16];                             // conv biases

    const int tid  = threadIdx.x;
    const int wv   = tid >> 6;
    const int lane = tid & 63;
    const int m    = lane & 15;
    const int g    = lane >> 4;

    // ---- stage fc0 hi frag table + conv weights global->LDS
    #pragma unroll
    for (int e0 = 0; e0 < 1024; e0 += 256) {
        const int e = e0 + tid;
        const int4 v = *reinterpret_cast<const int4*>(pack + (size_t)e * 8);
        *reinterpret_cast<int4*>(&wlds[e * 4]) = v;
    }
    if (tid < 144) { cwl[0][tid] = p0_w[tid]; cwl[1][tid] = p1_w[tid]; }
    else if (tid < 160) { cbl[0][tid - 144] = p0_b[tid - 144]; cbl[1][tid - 144] = p1_b[tid - 144]; }

    // XCD-bijective swizzle: consecutive swizzled ids share an XCD's L2 (halo reuse)
    const int bid = (blockIdx.x & 7) * 128 + (blockIdx.x >> 3);
    const int blockbase = bid * 256;
    const int b = blockbase >> 14;

    const int ch = (g & 1) * 8;
    unsigned short* hb = hlds + (wv << 11);
    const int lb = lane << 2;
    const float prog = (float)step * (1.0f / (float)NSTEPS);

    // ---- block-invariant loads
    int snapmask = 0;
    if (step > 0) {
        #pragma unroll
        for (int t = 0; t < T; ++t)
            snapmask |= (acq[b * T + t] == step) ? (1 << t) : 0;
    }
    bf16x8 w1f[8];   // fc1 A-frags (W1 hi/lo), rows 16..23
    #pragma unroll
    for (int q = 0; q < 8; ++q)
        w1f[q] = *reinterpret_cast<const bf16x8*>(pack + ((16 + q) * 64 + lane) * 8);
    float bias[8];
    #pragma unroll
    for (int nt = 0; nt < 8; ++nt) bias[nt] = fc0_b[nt * 16 + m];

    __syncthreads();   // all LDS staging visible

    const float* pwl = (g >= 2) ? cwl[0] : cwl[1];
    const float* pbl = (g >= 2) ? cbl[0] : cbl[1];

    for (int t = 0; t < 4; ++t) {
        const int cellbase = blockbase + t * 64 + wv * 16;
        const int hrow  = (cellbase >> 7) & (H - 1);
        const int wbase = cellbase & (W - 1);
        const int wcol  = wbase + m;

        // ---- depthwise conv: lane (g,m) -> 8 ch of one conv at cell cellbase+m
        // g0: z2 ch0-7 | g1: z2 ch8-15 | g2: z1 ch0-7 | g3: z1 ch8-15
        float z[8], xcen[8];
        #pragma unroll
        for (int j = 0; j < 8; ++j) z[j] = pbl[ch + j];
        #pragma unroll
        for (int di = -1; di <= 1; ++di) {
            int hh = hrow + di; hh = (hh < 0) ? 1 : ((hh > H - 1) ? H - 2 : hh);
            #pragma unroll
            for (int dj = -1; dj <= 1; ++dj) {
                int ww = wcol + dj; ww = (ww < 0) ? 1 : ((ww > W - 1) ? W - 2 : ww);
                const float4* p4 = reinterpret_cast<const float4*>(
                    x_in + (((size_t)(b * H + hh) * W + ww) << 4) + ch);
                const float4 q0 = p4[0], q1 = p4[1];
                const float xv[8] = {q0.x, q0.y, q0.z, q0.w, q1.x, q1.y, q1.z, q1.w};
                const int tap = (di + 1) * 3 + (dj + 1);
                #pragma unroll
                for (int j = 0; j < 8; ++j)
                    z[j] = fmaf(xv[j], pwl[tap * 16 + ch + j], z[j]);
                if (di == 0 && dj == 0) {
                    #pragma unroll
                    for (int j = 0; j < 8; ++j) xcen[j] = xv[j];
                }
            }
        }
        const float4 xold4 = *reinterpret_cast<const float4*>(
            x_in + ((size_t)(cellbase + m) << 4) + (g << 2));

        // ---- A-frags (K=64: k0-31 = [x | z1], k32-63 = [z2 | prog | pad])
        bf16x8 a0h, a0l, a1h, a1l;
        #pragma unroll
        for (int j = 0; j < 8; ++j) {
            const float f0 = (g < 2) ? xcen[j] : z[j];
            const float f1 = (g < 2) ? z[j] : ((g == 2 && j == 0) ? prog : 0.0f);
            const unsigned short h0 = bf16_hi(f0);
            a0h[j] = (short)h0;  a0l[j] = (short)bf16_hi(f0 - bf16_f32(h0));
            const unsigned short h1 = bf16_hi(f1);
            a1h[j] = (short)h1;  a1l[j] = (short)bf16_hi(f1 - bf16_f32(h1));
        }

        // ---- fc0: (a_hi + a_lo) x b_hi per k-half; store h as bf16-hi
        //      lane(g,m) reg r -> h[cell g*4+r][hid nt*16+m]
        __builtin_amdgcn_s_setprio(1);
        #pragma unroll
        for (int nt = 0; nt < 8; ++nt) {
            const int rbo = nt << 9;
            const bf16x8 b0h = *reinterpret_cast<const bf16x8*>(&wlds[rbo + lb]);
            const bf16x8 b1h = *reinterpret_cast<const bf16x8*>(&wlds[rbo + 256 + lb]);
            f32x4 acc = {0.0f, 0.0f, 0.0f, 0.0f};
            acc = __builtin_amdgcn_mfma_f32_16x16x32_bf16(a0h, b0h, acc, 0, 0, 0);
            acc = __builtin_amdgcn_mfma_f32_16x16x32_bf16(a0l, b0h, acc, 0, 0, 0);
            acc = __builtin_amdgcn_mfma_f32_16x16x32_bf16(a1h, b1h, acc, 0, 0, 0);
            acc = __builtin_amdgcn_mfma_f32_16x16x32_bf16(a1l, b1h, acc, 0, 0, 0);
            // gran = hid>>3 = nt*2 + (m>>3); swizzled gran' = gran ^ cr (4-bit XOR)
            const int gran = (nt << 1) | (m >> 3);
            #pragma unroll
            for (int r = 0; r < 4; ++r) {
                const int cr = g * 4 + r;
                hb[cr * 128 + ((gran ^ cr) << 3) + (m & 7)] =
                    bf16_hi(fmaxf(acc[r] + bias[nt], 0.0f));
            }
        }
        __builtin_amdgcn_s_setprio(0);
        // no block barrier: hlds is wave-private, within-wave DS ordering suffices

        // ---- fc1 swapped (D2 = W1 . h^T), 2 products: w1hi*h_hi + w1lo*h_hi
        //      bh = h[cell m][hid ks*32+g*8 .. +7], pre-converted bf16 from LDS
        f32x4 acc2 = {0.0f, 0.0f, 0.0f, 0.0f};
        #pragma unroll
        for (int ks = 0; ks < 4; ++ks) {
            const bf16x8 bh = *reinterpret_cast<const bf16x8*>(
                &hb[m * 128 + ((((ks << 2) + g) ^ m) << 3)]);
            __builtin_amdgcn_s_setprio(1);
            acc2 = __builtin_amdgcn_mfma_f32_16x16x32_bf16(w1f[ks * 2 + 0], bh, acc2, 0, 0, 0);
            acc2 = __builtin_amdgcn_mfma_f32_16x16x32_bf16(w1f[ks * 2 + 1], bh, acc2, 0, 0, 0);
            __builtin_amdgcn_s_setprio(0);
        }

        // ---- epilogue: D2 lane(g,m) reg r -> dx[ch g*4+r][cell cellbase+m]
        const size_t cell = (size_t)(cellbase + m);
        float4 xn;
        xn.x = xold4.x + 1.0f / (1.0f + __expf(-acc2[0]));
        xn.y = xold4.y + 1.0f / (1.0f + __expf(-acc2[1]));
        xn.z = xold4.z + 1.0f / (1.0f + __expf(-acc2[2]));
        xn.w = xold4.w + 1.0f / (1.0f + __expf(-acc2[3]));
        *reinterpret_cast<float4*>(x_out + (cell << 4) + (g << 2)) = xn;
        if (snapmask) {
            #pragma unroll
            for (int tt = 0; tt < T; ++tt) {
                if (snapmask & (1 << tt)) {
                    *reinterpret_cast<float4*>(out + (size_t)(b * T + tt) * (H * W * C)
                        + (((size_t)hrow * W + wbase + m) << 4) + (g << 2)) = xn;
                }
            }
        }
    }
}

extern "C" void kernel_launch(void* const* d_in, const int* in_sizes, int n_in,
                              void* d_out, int out_size, void* d_ws, size_t ws_size,
                              hipStream_t stream) {
    const float* inputs = (const float*)d_in[0];
    const int*   acq    = (const int*)d_in[1];
    const float* p0_w   = (const float*)d_in[2];
    const float* p0_b   = (const float*)d_in[3];
    const float* p1_w   = (const float*)d_in[4];
    const float* p1_b   = (const float*)d_in[5];
    const float* fc0_w  = (const float*)d_in[6];
    const float* fc0_b  = (const float*)d_in[7];
    const float* fc1_w  = (const float*)d_in[8];
    float* out = (float*)d_out;

    const size_t state_elems = (size_t)B * H * W * C;   // 16 MB each
    float* bufA = (float*)d_ws;
    float* bufB = bufA + state_elems;
    unsigned short* pack = (unsigned short*)(bufB + state_elems);  // 24 KB

    zero_acq0<<<B * T, 256, 0, stream>>>(acq, out);
    prep_pack<<<1, 256, 0, stream>>>(fc0_w, fc1_w, pack);

    const int n_cells = B * H * W;                 // 262144
    const dim3 grid(n_cells / 256), block(256);    // 1024 blocks, 4 tiles each

    const float* xin = inputs;
    for (int step = 0; step < NSTEPS; ++step) {
        float* xout = (step & 1) ? bufB : bufA;
        nca_step<<<grid, block, 0, stream>>>(
            xin, xout, p0_w, p0_b, p1_w, p1_b,
            pack, fc0_b, acq, out, step);
        xin = xout;
    }
}